// Round 5
// baseline (255.335 us; speedup 1.0000x reference)
//
#include <hip/hip_runtime.h>

#define PI2 6.28318530717958647692f

// D = 10000 = 100 x 100; F = 5001; signals: 128 pos + 10 atom + 1 closure = 139
#define NSIG 139
#define FS   5120      // spectrum row stride (float2)

// ---------------- twiddle tables ----------------
__global__ void k_tables(float* __restrict__ t100c, float* __restrict__ t100s,
                         float* __restrict__ twc,   float* __restrict__ tws) {
  int idx = blockIdx.x * 256 + threadIdx.x;
  if (idx >= 10000) return;
  int j = idx / 100, m = idx % 100;
  int r1 = (j * m) % 100;
  float a1 = PI2 * (float)r1 * 0.01f;
  float s1, c1; sincosf(a1, &s1, &c1);
  t100c[idx] = c1; t100s[idx] = s1;
  int r2 = (j * m) % 10000;
  float a2 = PI2 * (float)r2 * 0.0001f;
  float s2, c2; sincosf(a2, &s2, &c2);
  twc[idx] = c2; tws[idx] = s2;
}

// ---------------- forward stage 1 (Hermitian-paired) ----------------
// For real x, X_pre[100-k1] = conj(X_pre[k1]); both share ar=SUM x*cos, as=SUM x*sin.
// Thread computes k1 in [0,50] x 4 n2, writes post-twiddle rows k1 AND (100-k1)%100.
// tiles/sig = 51*25 = 1275
__global__ __launch_bounds__(256, 2) void k_f1(
                     const float* __restrict__ atom, const float* __restrict__ pos,
                     const float* __restrict__ clo,
                     const float* __restrict__ t100c, const float* __restrict__ t100s,
                     const float* __restrict__ twc, const float* __restrict__ tws,
                     float2* __restrict__ Bbuf) {
  unsigned id = blockIdx.x * 256u + threadIdx.x;
  if (id >= NSIG * 1275u) return;
  unsigned sig = id / 1275u, t = id % 1275u;
  unsigned k1 = t / 25u, n2 = (t % 25u) * 4u;
  const float* xb = (sig < 128u) ? (pos + sig * 10000u)
                   : ((sig < 138u) ? (atom + (sig - 128u) * 10000u) : clo);
  float ar[4] = {}, as[4] = {};
#pragma unroll 10
  for (int n1 = 0; n1 < 100; ++n1) {
    const float4 xv = *(const float4*)(xb + n1 * 100 + n2);
    const float c = t100c[n1 * 100 + k1];
    const float s = t100s[n1 * 100 + k1];
    ar[0] += xv.x * c; as[0] += xv.x * s;
    ar[1] += xv.y * c; as[1] += xv.y * s;
    ar[2] += xv.z * c; as[2] += xv.z * s;
    ar[3] += xv.w * c; as[3] += xv.w * s;
  }
  unsigned rb = (100u - k1) % 100u;
  float2* rowA = Bbuf + sig * 10000u + k1 * 100u + n2;
  float2* rowB = Bbuf + sig * 10000u + rb * 100u + n2;
#pragma unroll
  for (int j = 0; j < 4; ++j) {
    // row k1:  (ar - i*as) * (cwA - i*swA)
    float cwA = twc[(n2 + j) * 100 + k1];
    float swA = tws[(n2 + j) * 100 + k1];
    rowA[j] = make_float2(ar[j] * cwA - as[j] * swA,
                          -(as[j] * cwA + ar[j] * swA));
    // row 100-k1: (ar + i*as) * (cwB - i*swB)
    float cwB = twc[(n2 + j) * 100 + rb];
    float swB = tws[(n2 + j) * 100 + rb];
    rowB[j] = make_float2(ar[j] * cwB + as[j] * swB,
                          as[j] * cwB - ar[j] * swB);
  }
}

// ---------------- forward stage 2: X[k1+100k2] = sum_n2 B[k1][n2] e^{-2pi i n2 k2/100} ----------------
// tile: 2 k1 x 2 k2; k2 FASTEST across lanes (B row broadcast, twiddle coalesced)
__global__ __launch_bounds__(256, 2) void k_f2(
                     const float2* __restrict__ Bbuf,
                     const float* __restrict__ t100c, const float* __restrict__ t100s,
                     float2* __restrict__ spec) {
  unsigned id = blockIdx.x * 256u + threadIdx.x;
  if (id >= NSIG * 1300u) return;
  unsigned sig = id / 1300u, t = id % 1300u;
  unsigned k1 = (t / 26u) * 2u;   // 50 groups
  unsigned k2 = (t % 26u) * 2u;   // 26 groups, k2 in [0,52)
  const float* brow0 = (const float*)(Bbuf + sig * 10000u + k1 * 100u);
  const float* brow1 = brow0 + 200;
  float re[2][2] = {}, im[2][2] = {};
#pragma unroll 5
  for (int n2 = 0; n2 < 100; n2 += 2) {
    const float4 b0 = *(const float4*)(brow0 + 2 * n2);  // (re,im) at n2, n2+1 of row k1
    const float4 b1 = *(const float4*)(brow1 + 2 * n2);  // row k1+1
    const float2 c0 = *(const float2*)(t100c + n2 * 100 + k2);
    const float2 s0 = *(const float2*)(t100s + n2 * 100 + k2);
    const float2 c1 = *(const float2*)(t100c + (n2 + 1) * 100 + k2);
    const float2 s1 = *(const float2*)(t100s + (n2 + 1) * 100 + k2);
    const float cc0[2] = {c0.x, c0.y}, ss0[2] = {s0.x, s0.y};
    const float cc1[2] = {c1.x, c1.y}, ss1[2] = {s1.x, s1.y};
#pragma unroll
    for (int j = 0; j < 2; ++j) {
      re[0][j] += b0.x * cc0[j] + b0.y * ss0[j];
      im[0][j] += b0.y * cc0[j] - b0.x * ss0[j];
      re[1][j] += b1.x * cc0[j] + b1.y * ss0[j];
      im[1][j] += b1.y * cc0[j] - b1.x * ss0[j];
      re[0][j] += b0.z * cc1[j] + b0.w * ss1[j];
      im[0][j] += b0.w * cc1[j] - b0.z * ss1[j];
      re[1][j] += b1.z * cc1[j] + b1.w * ss1[j];
      im[1][j] += b1.w * cc1[j] - b1.z * ss1[j];
    }
  }
#pragma unroll
  for (int i = 0; i < 2; ++i)
#pragma unroll
    for (int j = 0; j < 2; ++j) {
      unsigned k = (k1 + i) + 100u * (k2 + j);
      if (k <= 5000u)
        spec[sig * FS + k] = make_float2(re[i][j], im[i][j]);
    }
}

// ---------------- mix: freq[b,k] = sum_s tm*Fa[aidx]*Fp[s] + sum_r rm*Fp*Fp*Fc; Hermitian extend ----------------
__global__ __launch_bounds__(256, 2) void k_mix(
                      const float2* __restrict__ spec,
                      const float* __restrict__ tmask, const float* __restrict__ rmask,
                      const int* __restrict__ aidx, const int* __restrict__ rpos,
                      float2* __restrict__ G) {
  __shared__ float2 FaS[10][256];
  __shared__ float2 FcS[256];
  __shared__ float tmS[2][128];
  __shared__ int   aiS[2][128];
  __shared__ float rmS[2][8];
  __shared__ int   rpS[2][8][2];
  int tid = threadIdx.x;
  int k = blockIdx.x * 256 + tid;
  int kc = k > 5000 ? 5000 : k;
  int b0 = blockIdx.y * 2;
#pragma unroll
  for (int a = 0; a < 10; ++a) FaS[a][tid] = spec[(128 + a) * FS + kc];
  FcS[tid] = spec[138 * FS + kc];
  for (int i = tid; i < 2 * 128; i += 256) {
    int bb = i >> 7, ss = i & 127;
    tmS[bb][ss] = tmask[(b0 + bb) * 128 + ss];
    aiS[bb][ss] = aidx[(b0 + bb) * 128 + ss];
  }
  if (tid < 16) {
    int bb = tid >> 3, rr = tid & 7;
    rmS[bb][rr] = rmask[(b0 + bb) * 8 + rr];
    rpS[bb][rr][0] = rpos[((b0 + bb) * 8 + rr) * 2 + 0];
    rpS[bb][rr][1] = rpos[((b0 + bb) * 8 + rr) * 2 + 1];
  }
  __syncthreads();
  float fr[2] = {}, fi[2] = {};
#pragma unroll 8
  for (int s = 0; s < 128; ++s) {
    float2 fp = spec[s * FS + kc];
#pragma unroll
    for (int b = 0; b < 2; ++b) {
      int a = aiS[b][s];
      float tm = tmS[b][s];
      float2 fa = FaS[a][tid];
      float tr = fa.x * fp.x - fa.y * fp.y;
      float ti = fa.x * fp.y + fa.y * fp.x;
      fr[b] += tm * tr;
      fi[b] += tm * ti;
    }
  }
  float2 fc = FcS[tid];
#pragma unroll
  for (int r = 0; r < 8; ++r) {
#pragma unroll
    for (int b = 0; b < 2; ++b) {
      int p0 = rpS[b][r][0], p1 = rpS[b][r][1];
      float rm = rmS[b][r];
      float2 f0 = spec[p0 * FS + kc];
      float2 f1 = spec[p1 * FS + kc];
      float tr = f0.x * f1.x - f0.y * f1.y;
      float ti = f0.x * f1.y + f0.y * f1.x;
      float ur = tr * fc.x - ti * fc.y;
      float ui = tr * fc.y + ti * fc.x;
      fr[b] += rm * ur;
      fi[b] += rm * ui;
    }
  }
  if (k <= 5000) {
#pragma unroll
    for (int b = 0; b < 2; ++b) {
      float fib = (k == 0 || k == 5000) ? 0.0f : fi[b];  // exact Hermitian guard
      G[(size_t)(b0 + b) * 10000 + k] = make_float2(fr[b], fib);
      if (k >= 1 && k <= 4999)
        G[(size_t)(b0 + b) * 10000 + (10000 - k)] = make_float2(fr[b], -fib);
    }
  }
}

// ---------------- inverse stage 1 (Hermitian-halved) ----------------
// Bi[m1][n2] = (sum_n1 G[100n1+n2] e^{+2pi i n1 m1/100}) * e^{+2pi i n2 m1/10000}, n2 in [0,51]
// Cols 0,50 pre-scaled by 0.5 (col 51 by 0) so i2 is a uniform doubled sum.
// tile: 1 m1 x 2 n2 (col-pair fastest across lanes). tiles = 64*100*26
__global__ __launch_bounds__(256, 2) void k_i1(
                     const float2* __restrict__ G,
                     const float* __restrict__ t100c, const float* __restrict__ t100s,
                     const float* __restrict__ twc, const float* __restrict__ tws,
                     float2* __restrict__ Bi) {
  unsigned id = blockIdx.x * 256u + threadIdx.x;
  if (id >= 64u * 2600u) return;
  unsigned sig = id / 2600u, t = id % 2600u;
  unsigned m1 = t / 26u, n2 = (t % 26u) * 2u;
  const float* grow = (const float*)(G + sig * 10000u);
  float re0 = 0.f, im0 = 0.f, re1 = 0.f, im1 = 0.f;
#pragma unroll 10
  for (int n1 = 0; n1 < 100; ++n1) {
    const float4 gv = *(const float4*)(grow + (n1 * 100 + n2) * 2);  // 2 complex
    float c = t100c[n1 * 100 + m1];
    float s = t100s[n1 * 100 + m1];
    re0 += gv.x * c - gv.y * s;
    im0 += gv.y * c + gv.x * s;
    re1 += gv.z * c - gv.w * s;
    im1 += gv.w * c + gv.z * s;
  }
  float cw0 = twc[n2 * 100 + m1],       sw0 = tws[n2 * 100 + m1];
  float cw1 = twc[(n2 + 1) * 100 + m1], sw1 = tws[(n2 + 1) * 100 + m1];
  float w0 = (n2 == 0 || n2 == 50) ? 0.5f : 1.0f;
  float w1 = (n2 == 50) ? 0.0f : 1.0f;   // col 51 unused
  float4 outv;
  outv.x = (re0 * cw0 - im0 * sw0) * w0;
  outv.y = (im0 * cw0 + re0 * sw0) * w0;
  outv.z = (re1 * cw1 - im1 * sw1) * w1;
  outv.w = (im1 * cw1 + re1 * sw1) * w1;
  *(float4*)((float*)Bi + (sig * 5200u + m1 * 52u + n2) * 2) = outv;
}

// ---------------- inverse stage 2 (Hermitian-halved, real part) ----------------
// y[m1+100m2] = 2e-4 * 2 * sum_{n2=0}^{51} Re( Bi[m1][n2] e^{+2pi i n2 m2/100} )
// tile: 2 m1 x 2 m2; m2 FASTEST across lanes. tiles = 64*50*50
__global__ __launch_bounds__(256, 2) void k_i2(
                     const float2* __restrict__ Bi,
                     const float* __restrict__ t100c, const float* __restrict__ t100s,
                     float* __restrict__ mol) {
  unsigned id = blockIdx.x * 256u + threadIdx.x;
  if (id >= 64u * 2500u) return;
  unsigned sig = id / 2500u, t = id % 2500u;
  unsigned m1 = (t / 50u) * 2u;   // 50 groups
  unsigned m2 = (t % 50u) * 2u;   // 50 groups, fastest
  const float* b0 = (const float*)Bi + (sig * 5200u + m1 * 52u) * 2;
  const float* b1 = b0 + 104;
  float re[2][2] = {};
#pragma unroll 13
  for (int jj = 0; jj < 26; ++jj) {
    int n2 = 2 * jj;
    const float4 v0 = *(const float4*)(b0 + 2 * n2);
    const float4 v1 = *(const float4*)(b1 + 2 * n2);
    const float2 c0 = *(const float2*)(t100c + n2 * 100 + m2);
    const float2 s0 = *(const float2*)(t100s + n2 * 100 + m2);
    const float2 c1 = *(const float2*)(t100c + (n2 + 1) * 100 + m2);
    const float2 s1 = *(const float2*)(t100s + (n2 + 1) * 100 + m2);
    const float cc0[2] = {c0.x, c0.y}, ss0[2] = {s0.x, s0.y};
    const float cc1[2] = {c1.x, c1.y}, ss1[2] = {s1.x, s1.y};
#pragma unroll
    for (int j = 0; j < 2; ++j) {
      re[0][j] += v0.x * cc0[j] - v0.y * ss0[j];
      re[1][j] += v1.x * cc0[j] - v1.y * ss0[j];
      re[0][j] += v0.z * cc1[j] - v0.w * ss1[j];
      re[1][j] += v1.z * cc1[j] - v1.w * ss1[j];
    }
  }
#pragma unroll
  for (int i = 0; i < 2; ++i)
#pragma unroll
    for (int j = 0; j < 2; ++j)
      mol[sig * 10000u + (m1 + i) + 100u * (m2 + j)] = re[i][j] * 2e-4f;
}

// ---------------- projection: out[b,p] = sum_d mol[b,d] W[p,d] ; D split into 250 chunks of 40 ----------------
// thread tile: 4 p x 16 b  (1 B LDS per FMA; float4 W-row streams)
__global__ __launch_bounds__(256) void k_proj(const float* __restrict__ mol,
                                              const float* __restrict__ W,
                                              float* __restrict__ part) {
  __shared__ float molS[40 * 64];
  int tid = threadIdx.x;
  int d0 = blockIdx.x * 40;
  for (int i = tid; i < 40 * 64; i += 256)
    molS[i] = mol[(size_t)(i & 63) * 10000 + d0 + (i >> 6)];
  __syncthreads();
  int p0 = (tid & 63) * 4;
  int bh = (tid >> 6) * 16;
  float acc[4][16] = {};
  const float* w0 = W + (size_t)(p0 + 0) * 10000 + d0;
  const float* w1 = W + (size_t)(p0 + 1) * 10000 + d0;
  const float* w2 = W + (size_t)(p0 + 2) * 10000 + d0;
  const float* w3 = W + (size_t)(p0 + 3) * 10000 + d0;
#pragma unroll 4
  for (int dl = 0; dl < 40; ++dl) {
    const float wv[4] = {w0[dl], w1[dl], w2[dl], w3[dl]};
    const float4* m4 = (const float4*)(molS + dl * 64 + bh);
#pragma unroll
    for (int q = 0; q < 4; ++q) {
      float4 mv = m4[q];
#pragma unroll
      for (int pp = 0; pp < 4; ++pp) {
        acc[pp][4 * q + 0] += wv[pp] * mv.x;
        acc[pp][4 * q + 1] += wv[pp] * mv.y;
        acc[pp][4 * q + 2] += wv[pp] * mv.z;
        acc[pp][4 * q + 3] += wv[pp] * mv.w;
      }
    }
  }
#pragma unroll
  for (int b = 0; b < 16; ++b) {
    float4 v = make_float4(acc[0][b], acc[1][b], acc[2][b], acc[3][b]);
    *(float4*)(part + (size_t)blockIdx.x * 16384 + (bh + b) * 256 + p0) = v;
  }
}

// ---------------- reduce partials + bias ----------------
__global__ void k_red(const float* __restrict__ part, const float* __restrict__ bias,
                      float* __restrict__ out) {
  int tid = threadIdx.x;
  int b = blockIdx.x;
  float acc = bias[tid];
#pragma unroll 8
  for (int ch = 0; ch < 250; ++ch)
    acc += part[(size_t)ch * 16384 + b * 256 + tid];
  out[b * 256 + tid] = acc;
}

extern "C" void kernel_launch(void* const* d_in, const int* in_sizes, int n_in,
                              void* d_out, int out_size, void* d_ws, size_t ws_size,
                              hipStream_t stream) {
  const float* atom  = (const float*)d_in[0];   // [10,10000]
  const float* pos   = (const float*)d_in[1];   // [128,10000]
  const float* clo   = (const float*)d_in[2];   // [10000]
  const float* W     = (const float*)d_in[3];   // [256,10000]
  const float* bias  = (const float*)d_in[4];   // [256]
  const float* tmask = (const float*)d_in[5];   // [64,128]
  const float* rmask = (const float*)d_in[6];   // [64,8]
  const int*   aidx  = (const int*)d_in[7];     // [64,128]
  const int*   rpos  = (const int*)d_in[8];     // [64,8,2]
  float* out = (float*)d_out;                   // [64,256]

  char* ws = (char*)d_ws;
  size_t off = 0;
  auto alloc = [&](size_t n) { off = (off + 255) & ~(size_t)255; size_t o = off; off += n; return o; };
  float* t100c = (float*)(ws + alloc(10000 * 4));
  float* t100s = (float*)(ws + alloc(10000 * 4));
  float* twc   = (float*)(ws + alloc(10000 * 4));
  float* tws   = (float*)(ws + alloc(10000 * 4));
  char* regA   = ws + alloc(16777216);          // Bbuf (11.12MB) / Bi (3.33MB) / partials (16.4MB)
  float2* Bbuf = (float2*)regA;
  float2* Bi   = (float2*)regA;                 // Bi overlays Bbuf (f2 done reading before i1 writes)
  float*  part = (float*)regA;
  float2* spec = (float2*)(ws + alloc((size_t)NSIG * FS * 8));
  float2* G    = (float2*)(ws + alloc((size_t)64 * 10000 * 8));
  float*  mol  = (float*)(ws + alloc((size_t)64 * 10000 * 4));

  k_tables<<<dim3(40), dim3(256), 0, stream>>>(t100c, t100s, twc, tws);
  k_f1<<<dim3((NSIG * 1275 + 255) / 256), dim3(256), 0, stream>>>(atom, pos, clo, t100c, t100s, twc, tws, Bbuf);
  k_f2<<<dim3((NSIG * 1300 + 255) / 256), dim3(256), 0, stream>>>(Bbuf, t100c, t100s, spec);
  k_mix<<<dim3(20, 32), dim3(256), 0, stream>>>(spec, tmask, rmask, aidx, rpos, G);
  k_i1<<<dim3((64 * 2600 + 255) / 256), dim3(256), 0, stream>>>(G, t100c, t100s, twc, tws, Bi);
  k_i2<<<dim3((64 * 2500 + 255) / 256), dim3(256), 0, stream>>>(Bi, t100c, t100s, mol);
  k_proj<<<dim3(250), dim3(256), 0, stream>>>(mol, W, part);
  k_red<<<dim3(64), dim3(256), 0, stream>>>(part, bias, out);
}

// Round 6
// 223.159 us; speedup vs baseline: 1.1442x; 1.1442x over previous
//
#include <hip/hip_runtime.h>

#define PI2 6.28318530717958647692f

// D = 10000 = 100 x 100; F = 5001; signals: 128 pos + 10 atom + 1 closure = 139
#define NSIG 139
#define FS   5120      // spectrum row stride (float2)

// ---------------- twiddle tables ----------------
__global__ void k_tables(float* __restrict__ t100c, float* __restrict__ t100s,
                         float* __restrict__ twc,   float* __restrict__ tws) {
  int idx = blockIdx.x * 256 + threadIdx.x;
  if (idx >= 10000) return;
  int j = idx / 100, m = idx % 100;
  int r1 = (j * m) % 100;
  float a1 = PI2 * (float)r1 * 0.01f;
  float s1, c1; sincosf(a1, &s1, &c1);
  t100c[idx] = c1; t100s[idx] = s1;
  int r2 = (j * m) % 10000;
  float a2 = PI2 * (float)r2 * 0.0001f;
  float s2, c2; sincosf(a2, &s2, &c2);
  twc[idx] = c2; tws[idx] = s2;
}

// ---------------- forward stage 1 (Hermitian-paired, LDS-staged) ----------------
// Block = (sig, split). Signal x (10000 floats, 40 KB) staged in LDS once,
// then each thread computes one (k1, 4x n2) tile: ar=SUM x*cos, as=SUM x*sin,
// writing post-twiddle rows k1 AND (100-k1)%100. tiles/sig = 51*25 = 1275 (5 splits).
__global__ void k_f1(const float* __restrict__ atom, const float* __restrict__ pos,
                     const float* __restrict__ clo,
                     const float* __restrict__ t100c, const float* __restrict__ t100s,
                     const float* __restrict__ twc, const float* __restrict__ tws,
                     float2* __restrict__ Bbuf) {
  __shared__ float xs[10000];
  unsigned sig = blockIdx.x;
  const float* xb = (sig < 128u) ? (pos + sig * 10000u)
                   : ((sig < 138u) ? (atom + (sig - 128u) * 10000u) : clo);
  for (int i = threadIdx.x; i < 2500; i += 256)
    *(float4*)(xs + 4 * i) = *(const float4*)(xb + 4 * i);
  __syncthreads();
  unsigned tt = blockIdx.y * 256u + threadIdx.x;
  if (tt >= 1275u) return;
  unsigned k1 = tt / 25u, n2 = (tt % 25u) * 4u;
  float ar[4] = {}, as[4] = {};
#pragma unroll 4
  for (int n1 = 0; n1 < 100; ++n1) {
    const float4 xv = *(const float4*)(xs + n1 * 100 + n2);   // LDS, contiguous b128
    const float c = t100c[n1 * 100 + k1];                      // broadcast (L1)
    const float s = t100s[n1 * 100 + k1];
    ar[0] += xv.x * c; as[0] += xv.x * s;
    ar[1] += xv.y * c; as[1] += xv.y * s;
    ar[2] += xv.z * c; as[2] += xv.z * s;
    ar[3] += xv.w * c; as[3] += xv.w * s;
  }
  unsigned rb = (100u - k1) % 100u;
  float2* rowA = Bbuf + sig * 10000u + k1 * 100u + n2;
  float2* rowB = Bbuf + sig * 10000u + rb * 100u + n2;
#pragma unroll
  for (int j = 0; j < 4; ++j) {
    // row k1:  (ar - i*as) * (cwA - i*swA)
    float cwA = twc[(n2 + j) * 100 + k1];
    float swA = tws[(n2 + j) * 100 + k1];
    rowA[j] = make_float2(ar[j] * cwA - as[j] * swA,
                          -(as[j] * cwA + ar[j] * swA));
    // row 100-k1: (ar + i*as) * (cwB - i*swB)
    float cwB = twc[(n2 + j) * 100 + rb];
    float swB = tws[(n2 + j) * 100 + rb];
    rowB[j] = make_float2(ar[j] * cwB + as[j] * swB,
                          as[j] * cwB - ar[j] * swB);
  }
}

// ---------------- forward stage 2: X[k1+100k2] = sum_n2 B[k1][n2] e^{-2pi i n2 k2/100} ----------------
// tile: 2 k1 x 2 k2; k2 FASTEST across lanes (B row broadcast, twiddle coalesced)
__global__ void k_f2(const float2* __restrict__ Bbuf,
                     const float* __restrict__ t100c, const float* __restrict__ t100s,
                     float2* __restrict__ spec) {
  unsigned id = blockIdx.x * 256u + threadIdx.x;
  if (id >= NSIG * 1300u) return;
  unsigned sig = id / 1300u, t = id % 1300u;
  unsigned k1 = (t / 26u) * 2u;   // 50 groups
  unsigned k2 = (t % 26u) * 2u;   // 26 groups, k2 in [0,52)
  const float* brow0 = (const float*)(Bbuf + sig * 10000u + k1 * 100u);
  const float* brow1 = brow0 + 200;
  float re[2][2] = {}, im[2][2] = {};
#pragma unroll 4
  for (int n2 = 0; n2 < 100; n2 += 2) {
    const float4 b0 = *(const float4*)(brow0 + 2 * n2);  // (re,im) at n2, n2+1 of row k1
    const float4 b1 = *(const float4*)(brow1 + 2 * n2);  // row k1+1
    const float2 c0 = *(const float2*)(t100c + n2 * 100 + k2);
    const float2 s0 = *(const float2*)(t100s + n2 * 100 + k2);
    const float2 c1 = *(const float2*)(t100c + (n2 + 1) * 100 + k2);
    const float2 s1 = *(const float2*)(t100s + (n2 + 1) * 100 + k2);
    const float cc0[2] = {c0.x, c0.y}, ss0[2] = {s0.x, s0.y};
    const float cc1[2] = {c1.x, c1.y}, ss1[2] = {s1.x, s1.y};
#pragma unroll
    for (int j = 0; j < 2; ++j) {
      re[0][j] += b0.x * cc0[j] + b0.y * ss0[j];
      im[0][j] += b0.y * cc0[j] - b0.x * ss0[j];
      re[1][j] += b1.x * cc0[j] + b1.y * ss0[j];
      im[1][j] += b1.y * cc0[j] - b1.x * ss0[j];
      re[0][j] += b0.z * cc1[j] + b0.w * ss1[j];
      im[0][j] += b0.w * cc1[j] - b0.z * ss1[j];
      re[1][j] += b1.z * cc1[j] + b1.w * ss1[j];
      im[1][j] += b1.w * cc1[j] - b1.z * ss1[j];
    }
  }
#pragma unroll
  for (int i = 0; i < 2; ++i)
#pragma unroll
    for (int j = 0; j < 2; ++j) {
      unsigned k = (k1 + i) + 100u * (k2 + j);
      if (k <= 5000u)
        spec[sig * FS + k] = make_float2(re[i][j], im[i][j]);
    }
}

// ---------------- mix: freq[b,k] = sum_s tm*Fa[aidx]*Fp[s] + sum_r rm*Fp*Fp*Fc; Hermitian extend ----------------
__global__ void k_mix(const float2* __restrict__ spec,
                      const float* __restrict__ tmask, const float* __restrict__ rmask,
                      const int* __restrict__ aidx, const int* __restrict__ rpos,
                      float2* __restrict__ G) {
  __shared__ float2 FaS[10][256];
  __shared__ float2 FcS[256];
  __shared__ float tmS[2][128];
  __shared__ int   aiS[2][128];
  __shared__ float rmS[2][8];
  __shared__ int   rpS[2][8][2];
  int tid = threadIdx.x;
  int k = blockIdx.x * 256 + tid;
  int kc = k > 5000 ? 5000 : k;
  int b0 = blockIdx.y * 2;
#pragma unroll
  for (int a = 0; a < 10; ++a) FaS[a][tid] = spec[(128 + a) * FS + kc];
  FcS[tid] = spec[138 * FS + kc];
  for (int i = tid; i < 2 * 128; i += 256) {
    int bb = i >> 7, ss = i & 127;
    tmS[bb][ss] = tmask[(b0 + bb) * 128 + ss];
    aiS[bb][ss] = aidx[(b0 + bb) * 128 + ss];
  }
  if (tid < 16) {
    int bb = tid >> 3, rr = tid & 7;
    rmS[bb][rr] = rmask[(b0 + bb) * 8 + rr];
    rpS[bb][rr][0] = rpos[((b0 + bb) * 8 + rr) * 2 + 0];
    rpS[bb][rr][1] = rpos[((b0 + bb) * 8 + rr) * 2 + 1];
  }
  __syncthreads();
  float fr[2] = {}, fi[2] = {};
#pragma unroll 4
  for (int s = 0; s < 128; ++s) {
    float2 fp = spec[s * FS + kc];
#pragma unroll
    for (int b = 0; b < 2; ++b) {
      int a = aiS[b][s];
      float tm = tmS[b][s];
      float2 fa = FaS[a][tid];
      float tr = fa.x * fp.x - fa.y * fp.y;
      float ti = fa.x * fp.y + fa.y * fp.x;
      fr[b] += tm * tr;
      fi[b] += tm * ti;
    }
  }
  float2 fc = FcS[tid];
#pragma unroll
  for (int r = 0; r < 8; ++r) {
#pragma unroll
    for (int b = 0; b < 2; ++b) {
      int p0 = rpS[b][r][0], p1 = rpS[b][r][1];
      float rm = rmS[b][r];
      float2 f0 = spec[p0 * FS + kc];
      float2 f1 = spec[p1 * FS + kc];
      float tr = f0.x * f1.x - f0.y * f1.y;
      float ti = f0.x * f1.y + f0.y * f1.x;
      float ur = tr * fc.x - ti * fc.y;
      float ui = tr * fc.y + ti * fc.x;
      fr[b] += rm * ur;
      fi[b] += rm * ui;
    }
  }
  if (k <= 5000) {
#pragma unroll
    for (int b = 0; b < 2; ++b) {
      float fib = (k == 0 || k == 5000) ? 0.0f : fi[b];  // exact Hermitian guard
      G[(size_t)(b0 + b) * 10000 + k] = make_float2(fr[b], fib);
      if (k >= 1 && k <= 4999)
        G[(size_t)(b0 + b) * 10000 + (10000 - k)] = make_float2(fr[b], -fib);
    }
  }
}

// ---------------- inverse stage 1 (Hermitian-halved, LDS-staged) ----------------
// Block = (sig, split). G[sig] cols 0..51 of all 100 rows staged in LDS (41.6 KB),
// then each thread computes a 2 m1 x 2 n2 tile (one gv load feeds 16 FMAs):
// Bi[m1][n2] = (sum_n1 G[100n1+n2] e^{+2pi i n1 m1/100}) * e^{+2pi i n2 m1/10000}.
// Cols 0,50 pre-scaled by 0.5 (col 51 by 0) so i2 is a uniform doubled sum.
// tiles/sig = 50*26 = 1300 (6 splits).
__global__ void k_i1(const float2* __restrict__ G,
                     const float* __restrict__ t100c, const float* __restrict__ t100s,
                     const float* __restrict__ twc, const float* __restrict__ tws,
                     float2* __restrict__ Bi) {
  __shared__ float gs[10400];   // 100 rows x 52 complex (104 floats/row)
  unsigned sig = blockIdx.x;
  const float* gp = (const float*)(G + sig * 10000u);
  for (int i = threadIdx.x; i < 2600; i += 256) {
    int row = i / 26, c4 = i % 26;
    *(float4*)(gs + row * 104 + c4 * 4) = *(const float4*)(gp + row * 200 + c4 * 4);
  }
  __syncthreads();
  unsigned tt = blockIdx.y * 256u + threadIdx.x;
  if (tt >= 1300u) return;
  unsigned m1 = (tt / 26u) * 2u, n2 = (tt % 26u) * 2u;
  float reA[2] = {}, imA[2] = {};   // col n2   for m1, m1+1
  float reB[2] = {}, imB[2] = {};   // col n2+1 for m1, m1+1
#pragma unroll 4
  for (int n1 = 0; n1 < 100; ++n1) {
    const float4 gv = *(const float4*)(gs + n1 * 104 + n2 * 2);  // 2 complex, LDS
    const float2 cv = *(const float2*)(t100c + n1 * 100 + m1);
    const float2 sv = *(const float2*)(t100s + n1 * 100 + m1);
    const float cc[2] = {cv.x, cv.y};
    const float ss[2] = {sv.x, sv.y};
#pragma unroll
    for (int i = 0; i < 2; ++i) {
      reA[i] += gv.x * cc[i] - gv.y * ss[i];
      imA[i] += gv.y * cc[i] + gv.x * ss[i];
      reB[i] += gv.z * cc[i] - gv.w * ss[i];
      imB[i] += gv.w * cc[i] + gv.z * ss[i];
    }
  }
  float w0 = (n2 == 0 || n2 == 50) ? 0.5f : 1.0f;
  float w1 = (n2 == 50) ? 0.0f : 1.0f;   // col 51 unused
#pragma unroll
  for (int i = 0; i < 2; ++i) {
    float cw0 = twc[n2 * 100 + m1 + i],       sw0 = tws[n2 * 100 + m1 + i];
    float cw1 = twc[(n2 + 1) * 100 + m1 + i], sw1 = tws[(n2 + 1) * 100 + m1 + i];
    float4 outv;
    outv.x = (reA[i] * cw0 - imA[i] * sw0) * w0;
    outv.y = (imA[i] * cw0 + reA[i] * sw0) * w0;
    outv.z = (reB[i] * cw1 - imB[i] * sw1) * w1;
    outv.w = (imB[i] * cw1 + reB[i] * sw1) * w1;
    *(float4*)((float*)Bi + (sig * 5200u + (m1 + i) * 52u + n2) * 2) = outv;
  }
}

// ---------------- inverse stage 2 (Hermitian-halved, real part) ----------------
// y[m1+100m2] = 2e-4 * 2 * sum_{n2=0}^{51} Re( Bi[m1][n2] e^{+2pi i n2 m2/100} )
// tile: 2 m1 x 2 m2; m2 FASTEST across lanes. tiles = 64*50*50
__global__ void k_i2(const float2* __restrict__ Bi,
                     const float* __restrict__ t100c, const float* __restrict__ t100s,
                     float* __restrict__ mol) {
  unsigned id = blockIdx.x * 256u + threadIdx.x;
  if (id >= 64u * 2500u) return;
  unsigned sig = id / 2500u, t = id % 2500u;
  unsigned m1 = (t / 50u) * 2u;   // 50 groups
  unsigned m2 = (t % 50u) * 2u;   // 50 groups, fastest
  const float* b0 = (const float*)Bi + (sig * 5200u + m1 * 52u) * 2;
  const float* b1 = b0 + 104;
  float re[2][2] = {};
#pragma unroll 4
  for (int jj = 0; jj < 26; ++jj) {
    int n2 = 2 * jj;
    const float4 v0 = *(const float4*)(b0 + 2 * n2);
    const float4 v1 = *(const float4*)(b1 + 2 * n2);
    const float2 c0 = *(const float2*)(t100c + n2 * 100 + m2);
    const float2 s0 = *(const float2*)(t100s + n2 * 100 + m2);
    const float2 c1 = *(const float2*)(t100c + (n2 + 1) * 100 + m2);
    const float2 s1 = *(const float2*)(t100s + (n2 + 1) * 100 + m2);
    const float cc0[2] = {c0.x, c0.y}, ss0[2] = {s0.x, s0.y};
    const float cc1[2] = {c1.x, c1.y}, ss1[2] = {s1.x, s1.y};
#pragma unroll
    for (int j = 0; j < 2; ++j) {
      re[0][j] += v0.x * cc0[j] - v0.y * ss0[j];
      re[1][j] += v1.x * cc0[j] - v1.y * ss0[j];
      re[0][j] += v0.z * cc1[j] - v0.w * ss1[j];
      re[1][j] += v1.z * cc1[j] - v1.w * ss1[j];
    }
  }
#pragma unroll
  for (int i = 0; i < 2; ++i)
#pragma unroll
    for (int j = 0; j < 2; ++j)
      mol[sig * 10000u + (m1 + i) + 100u * (m2 + j)] = re[i][j] * 2e-4f;
}

// ---------------- projection: out[b,p] = sum_d mol[b,d] W[p,d] ; D split into 250 chunks of 40 ----------------
// thread tile: 4 p x 16 b  (1 B LDS per FMA; float4 W-row streams)
__global__ __launch_bounds__(256) void k_proj(const float* __restrict__ mol,
                                              const float* __restrict__ W,
                                              float* __restrict__ part) {
  __shared__ float molS[40 * 64];
  int tid = threadIdx.x;
  int d0 = blockIdx.x * 40;
  for (int i = tid; i < 40 * 64; i += 256)
    molS[i] = mol[(size_t)(i & 63) * 10000 + d0 + (i >> 6)];
  __syncthreads();
  int p0 = (tid & 63) * 4;
  int bh = (tid >> 6) * 16;
  float acc[4][16] = {};
  const float* w0 = W + (size_t)(p0 + 0) * 10000 + d0;
  const float* w1 = W + (size_t)(p0 + 1) * 10000 + d0;
  const float* w2 = W + (size_t)(p0 + 2) * 10000 + d0;
  const float* w3 = W + (size_t)(p0 + 3) * 10000 + d0;
#pragma unroll 4
  for (int dl = 0; dl < 40; ++dl) {
    const float wv[4] = {w0[dl], w1[dl], w2[dl], w3[dl]};
    const float4* m4 = (const float4*)(molS + dl * 64 + bh);
#pragma unroll
    for (int q = 0; q < 4; ++q) {
      float4 mv = m4[q];
#pragma unroll
      for (int pp = 0; pp < 4; ++pp) {
        acc[pp][4 * q + 0] += wv[pp] * mv.x;
        acc[pp][4 * q + 1] += wv[pp] * mv.y;
        acc[pp][4 * q + 2] += wv[pp] * mv.z;
        acc[pp][4 * q + 3] += wv[pp] * mv.w;
      }
    }
  }
#pragma unroll
  for (int b = 0; b < 16; ++b) {
    float4 v = make_float4(acc[0][b], acc[1][b], acc[2][b], acc[3][b]);
    *(float4*)(part + (size_t)blockIdx.x * 16384 + (bh + b) * 256 + p0) = v;
  }
}

// ---------------- reduce partials + bias ----------------
__global__ void k_red(const float* __restrict__ part, const float* __restrict__ bias,
                      float* __restrict__ out) {
  int tid = threadIdx.x;
  int b = blockIdx.x;
  float acc = bias[tid];
#pragma unroll 8
  for (int ch = 0; ch < 250; ++ch)
    acc += part[(size_t)ch * 16384 + b * 256 + tid];
  out[b * 256 + tid] = acc;
}

extern "C" void kernel_launch(void* const* d_in, const int* in_sizes, int n_in,
                              void* d_out, int out_size, void* d_ws, size_t ws_size,
                              hipStream_t stream) {
  const float* atom  = (const float*)d_in[0];   // [10,10000]
  const float* pos   = (const float*)d_in[1];   // [128,10000]
  const float* clo   = (const float*)d_in[2];   // [10000]
  const float* W     = (const float*)d_in[3];   // [256,10000]
  const float* bias  = (const float*)d_in[4];   // [256]
  const float* tmask = (const float*)d_in[5];   // [64,128]
  const float* rmask = (const float*)d_in[6];   // [64,8]
  const int*   aidx  = (const int*)d_in[7];     // [64,128]
  const int*   rpos  = (const int*)d_in[8];     // [64,8,2]
  float* out = (float*)d_out;                   // [64,256]

  char* ws = (char*)d_ws;
  size_t off = 0;
  auto alloc = [&](size_t n) { off = (off + 255) & ~(size_t)255; size_t o = off; off += n; return o; };
  float* t100c = (float*)(ws + alloc(10000 * 4));
  float* t100s = (float*)(ws + alloc(10000 * 4));
  float* twc   = (float*)(ws + alloc(10000 * 4));
  float* tws   = (float*)(ws + alloc(10000 * 4));
  char* regA   = ws + alloc(16777216);          // Bbuf (11.12MB) / Bi (3.33MB) / partials (16.4MB)
  float2* Bbuf = (float2*)regA;
  float2* Bi   = (float2*)regA;                 // Bi overlays Bbuf (f2 done reading before i1 writes)
  float*  part = (float*)regA;
  float2* spec = (float2*)(ws + alloc((size_t)NSIG * FS * 8));
  float2* G    = (float2*)(ws + alloc((size_t)64 * 10000 * 8));
  float*  mol  = (float*)(ws + alloc((size_t)64 * 10000 * 4));

  k_tables<<<dim3(40), dim3(256), 0, stream>>>(t100c, t100s, twc, tws);
  k_f1<<<dim3(NSIG, 5), dim3(256), 0, stream>>>(atom, pos, clo, t100c, t100s, twc, tws, Bbuf);
  k_f2<<<dim3((NSIG * 1300 + 255) / 256), dim3(256), 0, stream>>>(Bbuf, t100c, t100s, spec);
  k_mix<<<dim3(20, 32), dim3(256), 0, stream>>>(spec, tmask, rmask, aidx, rpos, G);
  k_i1<<<dim3(64, 6), dim3(256), 0, stream>>>(G, t100c, t100s, twc, tws, Bi);
  k_i2<<<dim3((64 * 2500 + 255) / 256), dim3(256), 0, stream>>>(Bi, t100c, t100s, mol);
  k_proj<<<dim3(250), dim3(256), 0, stream>>>(mol, W, part);
  k_red<<<dim3(64), dim3(256), 0, stream>>>(part, bias, out);
}